// Round 8
// baseline (263.135 us; speedup 1.0000x reference)
//
#include <hip/hip_runtime.h>

#define N 8192

typedef float f32x4 __attribute__((ext_vector_type(4)));

#define RPB 8     // rows per block (2 per wave)
#define KL  20    // k-slots (of 32) in LDS per row -> 40960 B/block (4 blocks/CU = 160 KiB)
                  // slots KL..31 (12) in 3 named uint4 per row per lane

#define NBLK (N / RPB)   // 1024 cooperative blocks

__device__ __forceinline__ unsigned int qpack(f32x4 v, float& s) {
    s += (v.x + v.y) + (v.z + v.w);
    unsigned int b0 = __float2uint_rn(v.x * 255.0f);
    unsigned int b1 = __float2uint_rn(v.y * 255.0f);
    unsigned int b2 = __float2uint_rn(v.z * 255.0f);
    unsigned int b3 = __float2uint_rn(v.w * 255.0f);
    return b0 | (b1 << 8) | (b2 << 16) | (b3 << 24);
}

__device__ __forceinline__ void emit(unsigned int b, float ris,
                                     const f32x4* __restrict__ c4, f32x4* __restrict__ o) {
    f32x4 f;                       // v_cvt_f32_ubyte0..3
    f.x = (float)(b & 0xffu);
    f.y = (float)((b >> 8) & 0xffu);
    f.z = (float)((b >> 16) & 0xffu);
    f.w = (float)(b >> 24);
    __builtin_nontemporal_store(f * ris * (*c4), o);
}

// Lightweight grid barrier: counter pre-zeroed by hipMemsetAsync each launch.
// Agent-scope release fence -> arrive -> spin (short sleep) -> acquire fence.
// The fences writeback/invalidate per-XCD L2 so dinv is coherent device-wide.
__device__ __forceinline__ void grid_barrier(unsigned int* cnt) {
    __syncthreads();
    if (threadIdx.x == 0) {
        __builtin_amdgcn_fence(__ATOMIC_RELEASE, "agent");   // flush dinv to HBM/IC
        __hip_atomic_fetch_add(cnt, 1u, __ATOMIC_RELAXED, __HIP_MEMORY_SCOPE_AGENT);
        while (__hip_atomic_load(cnt, __ATOMIC_RELAXED, __HIP_MEMORY_SCOPE_AGENT) < (unsigned)NBLK)
            __builtin_amdgcn_s_sleep(2);
        __builtin_amdgcn_fence(__ATOMIC_ACQUIRE, "agent");   // invalidate local L2
    }
    __syncthreads();
}

// ===================== fused cooperative single-pass (v3: fast barrier) =====
__global__ __launch_bounds__(256, 4) void fused_kernel(const float* __restrict__ A,
                                                       float* __restrict__ dinv,
                                                       unsigned int* __restrict__ barrier_cnt,
                                                       float* __restrict__ out) {
    __shared__ unsigned int qlds[RPB * KL * 64];   // 40960 B

    const int wave = threadIdx.x >> 6;
    const int lane = threadIdx.x & 63;
    const int row0 = blockIdx.x * RPB;

    uint4 q00, q01, q02;   // row (wave*2+0), slots 20..31
    uint4 q10, q11, q12;   // row (wave*2+1), slots 20..31

    // ---- phase 1: rowsum + quantize (A read once, nt) ----
#define P1_ROW(R, Q0, Q1, Q2)                                                   \
    {                                                                           \
        const int wrow = wave * 2 + (R);                                        \
        const int row  = row0 + wrow;                                           \
        const f32x4* arow = reinterpret_cast<const f32x4*>(A + (size_t)row * N);\
        float s = 0.0f;                                                         \
        _Pragma("unroll")                                                       \
        for (int k = 0; k < KL; ++k) {                                          \
            f32x4 v = __builtin_nontemporal_load(&arow[k * 64 + lane]);         \
            qlds[(wrow * KL + k) * 64 + lane] = qpack(v, s);                    \
        }                                                                       \
        Q0.x = qpack(__builtin_nontemporal_load(&arow[(KL + 0) * 64 + lane]), s); \
        Q0.y = qpack(__builtin_nontemporal_load(&arow[(KL + 1) * 64 + lane]), s); \
        Q0.z = qpack(__builtin_nontemporal_load(&arow[(KL + 2) * 64 + lane]), s); \
        Q0.w = qpack(__builtin_nontemporal_load(&arow[(KL + 3) * 64 + lane]), s); \
        Q1.x = qpack(__builtin_nontemporal_load(&arow[(KL + 4) * 64 + lane]), s); \
        Q1.y = qpack(__builtin_nontemporal_load(&arow[(KL + 5) * 64 + lane]), s); \
        Q1.z = qpack(__builtin_nontemporal_load(&arow[(KL + 6) * 64 + lane]), s); \
        Q1.w = qpack(__builtin_nontemporal_load(&arow[(KL + 7) * 64 + lane]), s); \
        Q2.x = qpack(__builtin_nontemporal_load(&arow[(KL + 8) * 64 + lane]), s); \
        Q2.y = qpack(__builtin_nontemporal_load(&arow[(KL + 9) * 64 + lane]), s); \
        Q2.z = qpack(__builtin_nontemporal_load(&arow[(KL +10) * 64 + lane]), s); \
        Q2.w = qpack(__builtin_nontemporal_load(&arow[(KL +11) * 64 + lane]), s); \
        _Pragma("unroll")                                                       \
        for (int off = 32; off >= 1; off >>= 1) s += __shfl_xor(s, off, 64);    \
        if (lane == 0) dinv[row] = 1.0f / sqrtf(s);                             \
    }

    P1_ROW(0, q00, q01, q02)
    P1_ROW(1, q10, q11, q12)
#undef P1_ROW

    grid_barrier(barrier_cnt);

    // ---- phase 2: dequant + scale + nt-store ----
    const f32x4* d4 = reinterpret_cast<const f32x4*>(dinv);

#define P2_ROW(R, Q0, Q1, Q2)                                                   \
    {                                                                           \
        const int wrow = wave * 2 + (R);                                        \
        const int row  = row0 + wrow;                                           \
        const float ris = dinv[row] * (1.0f / 255.0f);                          \
        f32x4* orow = reinterpret_cast<f32x4*>(out + (size_t)row * N);          \
        _Pragma("unroll")                                                       \
        for (int k = 0; k < KL; ++k)                                            \
            emit(qlds[(wrow * KL + k) * 64 + lane], ris,                        \
                 &d4[k * 64 + lane], &orow[k * 64 + lane]);                     \
        emit(Q0.x, ris, &d4[(KL + 0) * 64 + lane], &orow[(KL + 0) * 64 + lane]); \
        emit(Q0.y, ris, &d4[(KL + 1) * 64 + lane], &orow[(KL + 1) * 64 + lane]); \
        emit(Q0.z, ris, &d4[(KL + 2) * 64 + lane], &orow[(KL + 2) * 64 + lane]); \
        emit(Q0.w, ris, &d4[(KL + 3) * 64 + lane], &orow[(KL + 3) * 64 + lane]); \
        emit(Q1.x, ris, &d4[(KL + 4) * 64 + lane], &orow[(KL + 4) * 64 + lane]); \
        emit(Q1.y, ris, &d4[(KL + 5) * 64 + lane], &orow[(KL + 5) * 64 + lane]); \
        emit(Q1.z, ris, &d4[(KL + 6) * 64 + lane], &orow[(KL + 6) * 64 + lane]); \
        emit(Q1.w, ris, &d4[(KL + 7) * 64 + lane], &orow[(KL + 7) * 64 + lane]); \
        emit(Q2.x, ris, &d4[(KL + 8) * 64 + lane], &orow[(KL + 8) * 64 + lane]); \
        emit(Q2.y, ris, &d4[(KL + 9) * 64 + lane], &orow[(KL + 9) * 64 + lane]); \
        emit(Q2.z, ris, &d4[(KL +10) * 64 + lane], &orow[(KL +10) * 64 + lane]); \
        emit(Q2.w, ris, &d4[(KL +11) * 64 + lane], &orow[(KL +11) * 64 + lane]); \
    }

    P2_ROW(0, q00, q01, q02)
    P2_ROW(1, q10, q11, q12)
#undef P2_ROW
}

// ===================== fallback: proven R5 two-pass (108 µs) =====================

__global__ __launch_bounds__(256) void rowsum_quant_kernel(const float* __restrict__ A,
                                                           float* __restrict__ dinv,
                                                           unsigned int* __restrict__ q) {
    const int wave = threadIdx.x >> 6;
    const int lane = threadIdx.x & 63;
    const int row  = blockIdx.x * 4 + wave;

    const f32x4*  arow = reinterpret_cast<const f32x4*>(A + (size_t)row * N);
    unsigned int* qrow = q + (size_t)row * (N / 4);

    float s = 0.0f;
#pragma unroll
    for (int k = 0; k < 32; ++k) {
        const int idx = k * 64 + lane;
        f32x4 v = __builtin_nontemporal_load(&arow[idx]);
        qrow[idx] = qpack(v, s);
    }
#pragma unroll
    for (int off = 32; off >= 1; off >>= 1)
        s += __shfl_xor(s, off, 64);
    if (lane == 0)
        dinv[row] = 1.0f / sqrtf(s);
}

__global__ __launch_bounds__(256) void scale_q_kernel(const unsigned int* __restrict__ q,
                                                      const float* __restrict__ dinv,
                                                      float* __restrict__ out) {
    const int row = (N - 1) - blockIdx.x;
    const float ris = dinv[row] * (1.0f / 255.0f);

    const unsigned int* qrow = q + (size_t)row * (N / 4);
    const f32x4* d4 = reinterpret_cast<const f32x4*>(dinv);
    f32x4*       o4 = reinterpret_cast<f32x4*>(out + (size_t)row * N);

#pragma unroll
    for (int k = 0; k < 8; ++k) {
        const int idx = k * 256 + threadIdx.x;
        emit(qrow[idx], ris, &d4[idx], &o4[idx]);
    }
}

extern "C" void kernel_launch(void* const* d_in, const int* in_sizes, int n_in,
                              void* d_out, int out_size, void* d_ws, size_t ws_size,
                              hipStream_t stream) {
    const float* A    = (const float*)d_in[0];
    float*       out  = (float*)d_out;
    float*        dinv = (float*)d_ws;                           // [0, 32KB)
    unsigned int* cnt  = (unsigned int*)((char*)d_ws + 32768);   // [32KB, +4)

    // Barrier counter must start at 0 every call (deterministic, capture-safe).
    hipMemsetAsync(cnt, 0, sizeof(unsigned int), stream);

    void* args[] = {(void*)&A, (void*)&dinv, (void*)&cnt, (void*)&out};
    hipError_t err = hipLaunchCooperativeKernel((const void*)fused_kernel,
                                                dim3(NBLK), dim3(256),
                                                args, 0, stream);
    if (err == hipSuccess) return;

    // Fallback: two-pass u8-shadow
    const size_t need = 65536 + (size_t)N * N;
    if (ws_size >= need) {
        unsigned int* q = (unsigned int*)((char*)d_ws + 65536);
        rowsum_quant_kernel<<<N / 4, 256, 0, stream>>>(A, dinv, q);
        scale_q_kernel<<<N, 256, 0, stream>>>(q, dinv, out);
    }
}